// Round 19
// baseline (1345.455 us; speedup 1.0000x reference)
//
#include <hip/hip_runtime.h>
#include <math.h>

// QPLayer: batched primal-dual IPM, Q=0, G=-I (LP). f64 inputs DELIVERED AS F32
// (established round 8). Schur complement S = A diag(s/z) A^T (40x40), solved
// with COMPLETE-DIAGONAL-PIVOTED LDL^T (greedy max pivot; load-bearing), lane i
// owns row i of S in registers.
// ROUND 19: occupancy. r18 was latency-chain bound at 1 wave/SIMD (VALUBusy
// 25%, stalls ~75%). Ald (20.8 KB) is batch-invariant -> pack 4 elements
// (4 waves) per 256-thread block sharing one Ald: LDS 79.9 KB -> 2 blocks/CU
// -> 2 waves/SIMD (double latency hiding). Each element remains one wave with
// wave-private buffers, so ALL intra-iteration barriers are dropped (r18's
// barrier-free Srow pattern proved wave-internal LDS ordering suffices); only
// the Ald setup barrier remains. P3's 40-instr lane-kt staging write replaced
// by the r17-proven 4x depth-10 select chain + ONE Srow[tid]=col scatter
// (halves LDS-pipe instructions, which 8 waves/CU now share).
// Bitwise-identical arithmetic to r18.

#define NXV   64
#define MEQ   40
#define NITER 25
#define ELEMS 4
#define SIGMA_C 0.1
#define FTB_C   0.99
#define SA 65    // LDS row stride for A (doubles)
#define SS 41    // LDS row stride for S staging (doubles); Sl reused for Lm
#define PIV_DROP_REL 1e-12

union DU { double d; int i[2]; unsigned u[2]; };

__device__ __forceinline__ double readlane_f64(double v, int lane) {
    DU a; a.d = v; DU r;
    r.i[0] = __builtin_amdgcn_readlane(a.i[0], lane);
    r.i[1] = __builtin_amdgcn_readlane(a.i[1], lane);
    return r.d;
}

// DPP wave64 reduction ladders (verified bit-exact rounds 16-18).
template<int CTRL>
__device__ __forceinline__ double dpp_add_step(double v) {
    DU a; a.d = v; DU b;
    b.i[0] = __builtin_amdgcn_update_dpp(0, a.i[0], CTRL, 0xf, 0xf, true);
    b.i[1] = __builtin_amdgcn_update_dpp(0, a.i[1], CTRL, 0xf, 0xf, true);
    return v + b.d;
}
__device__ __forceinline__ double wave_sum_f64(double v) {
    v = dpp_add_step<0x111>(v); v = dpp_add_step<0x112>(v);
    v = dpp_add_step<0x114>(v); v = dpp_add_step<0x118>(v);
    v = dpp_add_step<0x142>(v); v = dpp_add_step<0x143>(v);
    return readlane_f64(v, 63);
}
template<int CTRL>
__device__ __forceinline__ double dpp_min_step(double v) {   // identity +inf
    DU a; a.d = v; DU b;
    b.i[0] = __builtin_amdgcn_update_dpp(0x00000000, a.i[0], CTRL, 0xf, 0xf, false);
    b.i[1] = __builtin_amdgcn_update_dpp(0x7ff00000, a.i[1], CTRL, 0xf, 0xf, false);
    return fmin(v, b.d);
}
__device__ __forceinline__ double wave_min_f64(double v) {
    v = dpp_min_step<0x111>(v); v = dpp_min_step<0x112>(v);
    v = dpp_min_step<0x114>(v); v = dpp_min_step<0x118>(v);
    v = dpp_min_step<0x142>(v); v = dpp_min_step<0x143>(v);
    return readlane_f64(v, 63);
}
template<int CTRL>
__device__ __forceinline__ double dpp_max_step(double v) {   // identity -inf
    DU a; a.d = v; DU b;
    b.i[0] = __builtin_amdgcn_update_dpp(0x00000000, a.i[0], CTRL, 0xf, 0xf, false);
    b.i[1] = __builtin_amdgcn_update_dpp((int)0xfff00000u, a.i[1], CTRL, 0xf, 0xf, false);
    return fmax(v, b.d);
}
__device__ __forceinline__ double wave_max_f64(double v) {
    v = dpp_max_step<0x111>(v); v = dpp_max_step<0x112>(v);
    v = dpp_max_step<0x114>(v); v = dpp_max_step<0x118>(v);
    v = dpp_max_step<0x142>(v); v = dpp_max_step<0x143>(v);
    return readlane_f64(v, 63);
}
template<int CTRL>
__device__ __forceinline__ unsigned dpp_maxu_step(unsigned v) {
    unsigned m = (unsigned)__builtin_amdgcn_update_dpp(0, (int)v, CTRL, 0xf, 0xf, true);
    return v > m ? v : m;
}
__device__ __forceinline__ unsigned wave_max_u32(unsigned v) {
    v = dpp_maxu_step<0x111>(v); v = dpp_maxu_step<0x112>(v);
    v = dpp_maxu_step<0x114>(v); v = dpp_maxu_step<0x118>(v);
    v = dpp_maxu_step<0x142>(v); v = dpp_maxu_step<0x143>(v);
    return (unsigned)__builtin_amdgcn_readlane((int)v, 63);
}

__global__ __launch_bounds__(256, 2)
void qp_ipm_kernel(const float* __restrict__ puzzles,
                   const float* __restrict__ Af,
                   const float* __restrict__ lzf,
                   const float* __restrict__ uf,
                   float* __restrict__ out)
{
    __shared__ double Ald[MEQ * SA];              // 20,800 B (shared by 4 waves)
    __shared__ double Sl_a[ELEMS * MEQ * SS];     // 52,480 B
    __shared__ double dl_a[ELEMS * NXV];          //  2,048 B
    __shared__ double vl_a[ELEMS * NXV];          //  2,048 B (v in P1, dy in P5)
    __shared__ double Srow_a[ELEMS * MEQ];        //  1,280 B
    __shared__ double yl_a[ELEMS * MEQ];          //  1,280 B   => 79,936 B total

    const int t256 = threadIdx.x;
    const int wv   = t256 >> 6;        // element slot within block
    const int tid  = t256 & 63;        // lane
    const int b    = blockIdx.x * ELEMS + wv;
    const int row  = (tid < MEQ) ? tid : 0;

    double* __restrict__ Sl   = Sl_a   + wv * MEQ * SS;
    double* __restrict__ dl   = dl_a   + wv * NXV;
    double* __restrict__ vl   = vl_a   + wv * NXV;
    double* __restrict__ Srow = Srow_a + wv * MEQ;
    double* __restrict__ yl   = yl_a   + wv * MEQ;

    for (int e = t256; e < MEQ * NXV; e += 256)
        Ald[(e >> 6) * SA + (e & 63)] = (double)Af[e];
    dl[tid] = exp((double)lzf[tid]);
    if (tid < MEQ) yl[tid] = 0.0;
    __syncthreads();                   // ONLY cross-wave barrier (Ald setup)

    double b_r = 0.0;
    #pragma unroll 4
    for (int i = 0; i < NXV; ++i) b_r += Ald[row * SA + i] * dl[i];

    const double u_i = (double)uf[tid];
    const double p_i = -(double)puzzles[b * NXV + tid];
    double x_r = 0.0, s_r = 1.0, z_r = 1.0, y_r = 0.0;

    for (int it = 0; it < NITER; ++it) {
        // ---- P1: residuals/scalings; broadcasts via uniform LDS reads ----
        double aty = 0.0;
        #pragma unroll 4
        for (int j = 0; j < MEQ; ++j) aty += Ald[j * SA + tid] * yl[j];
        const double rd = p_i + aty - z_r;          // Q=0, G^T z = -z
        const double rs = s_r - x_r - u_i;          // -x + s - u
        const double mu = wave_sum_f64(s_r * z_r) * (1.0 / 64.0);
        const double rc = (SIGMA_C * mu - z_r * s_r + z_r * rs) / s_r;
        const double rx = rc - rd;                  // rhs_x
        const double d_r = s_r / z_r;
        const double v_r = d_r * rx + x_r;          // fy = A v - b
        vl[tid] = v_r;                              // wave-internal order: ok
        dl[tid] = d_r;

        double fy_r = 0.0;
        #pragma unroll 4
        for (int i = 0; i < NXV; ++i) fy_r += Ald[row * SA + i] * vl[i];
        fy_r -= b_r;

        // ---- P2: S = A diag(d) A^T, 4x4 lower tiles (lanes<55) -> LDS ----
        if (tid < 55) {
            int uu = tid, mb = 0;
            while (uu > mb) { uu -= (mb + 1); ++mb; }
            const int nb = uu;
            double a00=0,a01=0,a02=0,a03=0, a10=0,a11=0,a12=0,a13=0,
                   a20=0,a21=0,a22=0,a23=0, a30=0,a31=0,a32=0,a33=0;
            const double* Am = &Ald[(4 * mb) * SA];
            const double* An = &Ald[(4 * nb) * SA];
            for (int k = 0; k < NXV; ++k) {
                const double dk = dl[k];
                const double r0 = Am[0*SA+k], r1 = Am[1*SA+k], r2 = Am[2*SA+k], r3 = Am[3*SA+k];
                const double c0 = An[0*SA+k]*dk, c1 = An[1*SA+k]*dk, c2 = An[2*SA+k]*dk, c3 = An[3*SA+k]*dk;
                a00 += r0*c0; a01 += r0*c1; a02 += r0*c2; a03 += r0*c3;
                a10 += r1*c0; a11 += r1*c1; a12 += r1*c2; a13 += r1*c3;
                a20 += r2*c0; a21 += r2*c1; a22 += r2*c2; a23 += r2*c3;
                a30 += r3*c0; a31 += r3*c1; a32 += r3*c2; a33 += r3*c3;
            }
            double* Sp = &Sl[(4 * mb) * SS + 4 * nb];
            Sp[0*SS+0]=a00; Sp[0*SS+1]=a01; Sp[0*SS+2]=a02; Sp[0*SS+3]=a03;
            Sp[1*SS+0]=a10; Sp[1*SS+1]=a11; Sp[1*SS+2]=a12; Sp[1*SS+3]=a13;
            Sp[2*SS+0]=a20; Sp[2*SS+1]=a21; Sp[2*SS+2]=a22; Sp[2*SS+3]=a23;
            Sp[3*SS+0]=a30; Sp[3*SS+1]=a31; Sp[3*SS+2]=a32; Sp[3*SS+3]=a33;
        }

        // ---- load row tid of S into registers (symmetric fill) ----
        double Sreg[MEQ];
        double diag_r;
        if (tid < MEQ) {
            #pragma unroll
            for (int j = 0; j < MEQ; ++j)
                Sreg[j] = (j <= tid) ? Sl[tid * SS + j] : Sl[j * SS + tid];
            diag_r = Sl[tid * SS + tid];
        } else {
            #pragma unroll
            for (int j = 0; j < MEQ; ++j) Sreg[j] = 0.0;
            diag_r = -1.0e308;
        }
        const double dg  = wave_max_f64(diag_r);
        const double thr = dg * PIV_DROP_REL;

        // ---- P3: greedy-max-pivot LDL^T; col via select chain + 1 scatter ----
        double ip_own = 0.0;
        int    kk_own = 0;
        for (int t = 0; t < MEQ; ++t) {
            // packed-key argmax: sign-fixed hi32 of f64 | lane, DPP u32 max
            DU dd; dd.d = diag_r;
            const unsigned h  = dd.u[1];
            const unsigned mk = (h & 0x80000000u) ? ~h : (h | 0x80000000u);
            const unsigned key = wave_max_u32((mk & 0xFFFFFFC0u) | (unsigned)tid);
            const int kt = (int)(key & 63u);
            // col_i = S[i][kt] — 4 independent depth-10 chains + 3 combines
            double c0 = Sreg[0], c1 = Sreg[10], c2 = Sreg[20], c3 = Sreg[30];
            #pragma unroll
            for (int q = 1; q < 10; ++q) {
                if (kt == q)      c0 = Sreg[q];
                if (kt == 10 + q) c1 = Sreg[10 + q];
                if (kt == 20 + q) c2 = Sreg[20 + q];
                if (kt == 30 + q) c3 = Sreg[30 + q];
            }
            const double cl  = (kt < 10) ? c0 : c1;
            const double ch  = (kt < 30) ? c2 : c3;
            const double col = (kt < 20) ? cl : ch;

            const double piv  = readlane_f64(col, kt);      // lane kt: == diag
            double invP = 1.0 / piv;
            invP = (piv > thr) ? invP : 0.0;        // drop noise pivots
            if (tid == t) { kk_own = kt; ip_own = invP; }
            if (tid < MEQ) Srow[tid] = col;         // S[kt][i]==S[i][kt]: one scatter
            const double Lm = (diag_r > -1.0e307 && tid != kt) ? col * invP : 0.0;
            if (tid < MEQ) Sl[t * MEQ + tid] = Lm;  // multiplier -> dead Sl region
            const double fyk = readlane_f64(fy_r, kt);
            fy_r -= Lm * fyk;                       // unit-L forward solve
            #pragma unroll
            for (int j = 0; j < MEQ; ++j)           // rank-1: uniform broadcast reads
                Sreg[j] -= Lm * Srow[j];
            diag_r -= Lm * col;                     // selector maintenance
            if (tid == kt) diag_r = -1.0e308;       // eliminated
        }

        // ---- P4: backward solve; Lm prefetched into dead Sreg, static t ----
        #pragma unroll
        for (int t = 0; t < MEQ; ++t)
            Sreg[t] = (tid < MEQ) ? Sl[t * MEQ + tid] : 0.0;
        double X_r = 0.0;
        #pragma unroll
        for (int t = MEQ - 1; t >= 0; --t) {
            const double ssum = wave_sum_f64(Sreg[t] * X_r);
            const int    kt2  = __builtin_amdgcn_readlane(kk_own, t);
            const double ipt  = readlane_f64(ip_own, t);
            const double fyk  = readlane_f64(fy_r, kt2);
            double xt = fyk * ipt - ssum;
            xt = (ipt != 0.0) ? xt : 0.0;           // dropped direction -> 0
            X_r = (tid == kt2) ? xt : X_r;
        }
        if (tid < MEQ) vl[tid] = X_r;               // stage dy (vl dead since P1)

        // ---- P5: dx/ds/dz, ratio test (DPP min), updates ----
        double atdy = 0.0;
        #pragma unroll 4
        for (int j = 0; j < MEQ; ++j) atdy += Ald[j * SA + tid] * vl[j];
        const double dx = d_r * (rx - atdy);
        const double ds = dx - rs;                   // -rs + dx
        const double dz = rc - (z_r / s_r) * dx;
        double r = 1.0e300;
        if (ds < 0.0) r = -s_r / ds;
        if (dz < 0.0) r = fmin(r, -z_r / dz);
        r = wave_min_f64(r);
        const double alpha = fmin(1.0, FTB_C * r);
        x_r += alpha * dx;
        s_r += alpha * ds;
        z_r += alpha * dz;
        y_r += alpha * X_r;                          // X_r==0 for lanes>=40
        if (tid < MEQ) yl[tid] = y_r;                // stage y for next aty
    }

    out[b * NXV + tid] = (float)x_r;
}

extern "C" void kernel_launch(void* const* d_in, const int* in_sizes, int n_in,
                              void* d_out, int out_size, void* d_ws, size_t ws_size,
                              hipStream_t stream) {
    const float* puzzles = (const float*)d_in[0];
    const float* A       = (const float*)d_in[1];   // declared f64, delivered f32
    const float* logz0   = (const float*)d_in[2];
    // d_in[3] = Q (zeros, structural), d_in[4] = G (-I, structural)
    const float* u       = (const float*)d_in[5];
    float* out = (float*)d_out;

    const int n_batch = in_sizes[0] / NXV;   // 1024
    qp_ipm_kernel<<<n_batch / ELEMS, 256, 0, stream>>>(puzzles, A, logz0, u, out);
}